// Round 15
// baseline (113.911 us; speedup 1.0000x reference)
//
#include <hip/hip_runtime.h>
#include <hip/hip_bf16.h>

#define B_ROWS 4096
#define N2 8192
#define DD 512
#define NBLK 1056  // sum over P=0..63 of ceil((128-2P)/4)

typedef __attribute__((ext_vector_type(4))) float float4v;
typedef __attribute__((ext_vector_type(2))) long long2v;

// ---------- normalize + targets + rowsum-zero, one wave per row-pair ----------
// Outputs zn as fp8 e4m3 (OCP), 512 B per row.
__global__ __launch_bounds__(256) void k_norm_tgt(const float* __restrict__ f1,
                                                  const float* __restrict__ f2,
                                                  unsigned char* __restrict__ zn8,
                                                  float* __restrict__ tpart,
                                                  float* __restrict__ rowsum) {
  int w = threadIdx.x >> 6, lane = threadIdx.x & 63;
  int j = blockIdx.x * 4 + w;  // pair index 0..4095
  const float4* s1 = (const float4*)(f1 + (size_t)j * DD);
  const float4* s2 = (const float4*)(f2 + (size_t)j * DD);
  float4 a0 = s1[lane * 2], a1 = s1[lane * 2 + 1];
  float4 b0 = s2[lane * 2], b1 = s2[lane * 2 + 1];
  float ss1 = a0.x * a0.x + a0.y * a0.y + a0.z * a0.z + a0.w * a0.w +
              a1.x * a1.x + a1.y * a1.y + a1.z * a1.z + a1.w * a1.w;
  float ss2 = b0.x * b0.x + b0.y * b0.y + b0.z * b0.z + b0.w * b0.w +
              b1.x * b1.x + b1.y * b1.y + b1.z * b1.z + b1.w * b1.w;
  float ab = a0.x * b0.x + a0.y * b0.y + a0.z * b0.z + a0.w * b0.w +
             a1.x * b1.x + a1.y * b1.y + a1.z * b1.z + a1.w * b1.w;
#pragma unroll
  for (int o = 1; o < 64; o <<= 1) {
    ss1 += __shfl_xor(ss1, o, 64);
    ss2 += __shfl_xor(ss2, o, 64);
    ab += __shfl_xor(ab, o, 64);
  }
  float inv1 = 1.0f / fmaxf(sqrtf(ss1), 1e-8f);
  float inv2 = 1.0f / fmaxf(sqrtf(ss2), 1e-8f);

  uint2 q;
  int lo = __builtin_amdgcn_cvt_pk_fp8_f32(a0.x * inv1, a0.y * inv1, 0, false);
  lo = __builtin_amdgcn_cvt_pk_fp8_f32(a0.z * inv1, a0.w * inv1, lo, true);
  q.x = (unsigned int)lo;
  lo = __builtin_amdgcn_cvt_pk_fp8_f32(a1.x * inv1, a1.y * inv1, 0, false);
  lo = __builtin_amdgcn_cvt_pk_fp8_f32(a1.z * inv1, a1.w * inv1, lo, true);
  q.y = (unsigned int)lo;
  ((uint2*)(zn8 + (size_t)j * DD))[lane] = q;

  lo = __builtin_amdgcn_cvt_pk_fp8_f32(b0.x * inv2, b0.y * inv2, 0, false);
  lo = __builtin_amdgcn_cvt_pk_fp8_f32(b0.z * inv2, b0.w * inv2, lo, true);
  q.x = (unsigned int)lo;
  lo = __builtin_amdgcn_cvt_pk_fp8_f32(b1.x * inv2, b1.y * inv2, 0, false);
  lo = __builtin_amdgcn_cvt_pk_fp8_f32(b1.z * inv2, b1.w * inv2, lo, true);
  q.y = (unsigned int)lo;
  ((uint2*)(zn8 + (size_t)(B_ROWS + j) * DD))[lane] = q;

  if (lane == 0) tpart[j] = 2.0f + 2.0f * ab * inv1 * inv2;  // fp32-exact target terms
  if (threadIdx.x < 8) rowsum[blockIdx.x * 8 + threadIdx.x] = 0.f;  // 1024*8 = 8192
}

// ---------- main: persistent-A fp8 GEMM + exp-rowsum, NO LDS STAGING ----------
// zn8 (4 MB) is L2-resident: A panel (128 rows, full K) AND B cols load
// straight from L2 into registers. No __syncthreads in the main loop ->
// waves fully independent; MFMA overlaps L2 reads across 12 waves/CU.
// Tiles (P, j) for j in [2P, 128), chunks of 4; mirror col-sums for j >= 2P+2.
__global__ __launch_bounds__(256, 3) void k_gemm_expsum(const unsigned char* __restrict__ zn8,
                                                        float* __restrict__ rowsum) {
  __shared__ float colaccum[256];

  int g = blockIdx.x;  // natural order: round-robin dispatch balances XCDs

  // decode (P, c): band P has ceil((128-2P)/4) chunks of 4 col-tiles
  int P = 0, off = 0;
  for (;;) {
    int nb = (131 - 2 * P) >> 2;
    if (g < off + nb) break;
    off += nb;
    ++P;
  }
  int c = g - off;
  const int j0 = 2 * P + 4 * c;
  int nt = 128 - j0; if (nt > 4) nt = 4;

  const int tid = threadIdx.x;
  const int lane = tid & 63, w = tid >> 6;
  const int lr = lane & 15, hi2 = lane >> 4;
  const char* zb = (const char*)zn8;
  const int arow0 = P * 128;

  if (tid < 256) colaccum[tid] = 0.f;
  __syncthreads();  // only barrier before the final flush

  // ---- A panel: 32 rows per wave, full K, direct L2 -> regs (64 VGPR) ----
  long2v aR[2][8];
#pragma unroll
  for (int m = 0; m < 2; ++m) {
    const char* rowp = zb + (size_t)(arow0 + (w << 5) + (m << 4) + lr) * DD + hi2 * 16;
#pragma unroll
    for (int p = 0; p < 8; ++p)
      aR[m][p] = *(const long2v*)(rowp + p * 64);
  }

  float rowacc[2][4];
#pragma unroll
  for (int m = 0; m < 2; ++m)
#pragma unroll
    for (int r = 0; r < 4; ++r) rowacc[m][r] = 0.f;

  const float Cc = 2.88539008177792681f;

  for (int t = 0; t < nt; ++t) {
    const int jt = j0 + t;
    float4v acc[2][4];
#pragma unroll
    for (int m = 0; m < 2; ++m)
#pragma unroll
      for (int n = 0; n < 4; ++n) acc[m][n] = {0.f, 0.f, 0.f, 0.f};

#pragma unroll
    for (int n = 0; n < 4; ++n) {
      // B cols direct from L2: col = jt*64 + n*16 + lr, 8 x 16B k-windows
      long2v bR[8];
      const char* colp = zb + (size_t)(jt * 64 + (n << 4) + lr) * DD + hi2 * 16;
#pragma unroll
      for (int p = 0; p < 8; ++p)
        bR[p] = *(const long2v*)(colp + p * 64);
#pragma unroll
      for (int p = 0; p < 8; ++p)
#pragma unroll
        for (int m = 0; m < 2; ++m) {
          acc[m][n] = __builtin_amdgcn_mfma_f32_16x16x32_fp8_fp8(aR[m][p][0], bR[p][0], acc[m][n], 0, 0, 0);
          acc[m][n] = __builtin_amdgcn_mfma_f32_16x16x32_fp8_fp8(aR[m][p][1], bR[p][1], acc[m][n], 0, 0, 0);
        }
    }

    // epilogue tile t: e = exp(2*dot - 2) = exp2(C*dot - C)
    // D layout: row = w*32 + m*16 + hi2*4 + r, col = jt*64 + n*16 + lr
    float colp4[4] = {0.f, 0.f, 0.f, 0.f};
#pragma unroll
    for (int m = 0; m < 2; ++m)
#pragma unroll
      for (int n = 0; n < 4; ++n)
#pragma unroll
        for (int r = 0; r < 4; ++r) {
          float e = exp2f(fmaf(acc[m][n][r], Cc, -Cc));
          rowacc[m][r] += e;
          colp4[n] += e;
        }
    if (jt >= 2 * P + 2) {  // mirror col-sums (strictly above the diagonal band)
#pragma unroll
      for (int n = 0; n < 4; ++n) {
        float v = colp4[n];
        v += __shfl_xor(v, 16);
        v += __shfl_xor(v, 32);
        if (hi2 == 0) atomicAdd(&colaccum[(t << 6) + (n << 4) + lr], v);  // ds_add, no barrier
      }
    }
  }

  // row atomics: one per row per block (128 rows)
#pragma unroll
  for (int m = 0; m < 2; ++m)
#pragma unroll
    for (int r = 0; r < 4; ++r) {
      float v = rowacc[m][r];
      v += __shfl_xor(v, 1);
      v += __shfl_xor(v, 2);
      v += __shfl_xor(v, 4);
      v += __shfl_xor(v, 8);
      if (lr == 0)
        atomicAdd(&rowsum[arow0 + (w << 5) + (m << 4) + (hi2 << 2) + r], v);
    }

  // col mirror flush: once per block (skip the two diagonal tiles when c == 0)
  __syncthreads();
  for (int idx = tid + (c == 0 ? 128 : 0); idx < nt * 64; idx += 256)
    atomicAdd(&rowsum[(j0 + (idx >> 6)) * 64 + (idx & 63)], colaccum[idx]);
}

// ---------- finalize: loss = (sum(2 + log rowsum) - sum tpart) / 8192 ----------
__global__ __launch_bounds__(1024) void k_finalize(const float* __restrict__ rowsum,
                                                   const float* __restrict__ tpart,
                                                   float* __restrict__ out) {
  int t = threadIdx.x;
  float acc = 0.f;
  for (int i = t; i < N2; i += 1024) acc += 2.0f + logf(rowsum[i]);
  for (int i = t; i < B_ROWS; i += 1024) acc -= tpart[i];
#pragma unroll
  for (int o = 32; o; o >>= 1) acc += __shfl_down(acc, o, 64);
  __shared__ float wsum[16];
  if ((t & 63) == 0) wsum[t >> 6] = acc;
  __syncthreads();
  if (t == 0) {
    float s = 0.f;
#pragma unroll
    for (int k = 0; k < 16; ++k) s += wsum[k];
    out[0] = s * (1.0f / (float)N2);
  }
}

extern "C" void kernel_launch(void* const* d_in, const int* in_sizes, int n_in,
                              void* d_out, int out_size, void* d_ws, size_t ws_size,
                              hipStream_t stream) {
  const float* f1 = (const float*)d_in[0];
  const float* f2 = (const float*)d_in[1];
  float* out = (float*)d_out;
  char* ws = (char*)d_ws;

  unsigned char* zn8 = (unsigned char*)ws;               // 8192*512 = 4 MB fp8
  float* rowsum = (float*)(ws + (size_t)N2 * DD);        // 32 KB
  float* tpart = rowsum + N2;                            // 16 KB

  k_norm_tgt<<<B_ROWS / 4, 256, 0, stream>>>(f1, f2, zn8, tpart, rowsum);
  k_gemm_expsum<<<NBLK, 256, 0, stream>>>(zn8, rowsum);
  k_finalize<<<1, 1024, 0, stream>>>(rowsum, tpart, out);
}

// Round 16
// 70.807 us; speedup vs baseline: 1.6088x; 1.6088x over previous
//
#include <hip/hip_runtime.h>
#include <hip/hip_bf16.h>

#define B_ROWS 4096
#define N2 8192
#define DD 512
#define NBLK 1056  // sum over P=0..63 of ceil((128-2P)/4)

typedef __attribute__((ext_vector_type(4))) float float4v;
typedef __attribute__((ext_vector_type(2))) long long2v;

// ---------- normalize + targets + rowsum-zero, one wave per row-pair ----------
// Outputs zn as fp8 e4m3 (OCP), 512 B per row.
__global__ __launch_bounds__(256) void k_norm_tgt(const float* __restrict__ f1,
                                                  const float* __restrict__ f2,
                                                  unsigned char* __restrict__ zn8,
                                                  float* __restrict__ tpart,
                                                  float* __restrict__ rowsum) {
  int w = threadIdx.x >> 6, lane = threadIdx.x & 63;
  int j = blockIdx.x * 4 + w;  // pair index 0..4095
  const float4* s1 = (const float4*)(f1 + (size_t)j * DD);
  const float4* s2 = (const float4*)(f2 + (size_t)j * DD);
  float4 a0 = s1[lane * 2], a1 = s1[lane * 2 + 1];
  float4 b0 = s2[lane * 2], b1 = s2[lane * 2 + 1];
  float ss1 = a0.x * a0.x + a0.y * a0.y + a0.z * a0.z + a0.w * a0.w +
              a1.x * a1.x + a1.y * a1.y + a1.z * a1.z + a1.w * a1.w;
  float ss2 = b0.x * b0.x + b0.y * b0.y + b0.z * b0.z + b0.w * b0.w +
              b1.x * b1.x + b1.y * b1.y + b1.z * b1.z + b1.w * b1.w;
  float ab = a0.x * b0.x + a0.y * b0.y + a0.z * b0.z + a0.w * b0.w +
             a1.x * b1.x + a1.y * b1.y + a1.z * b1.z + a1.w * b1.w;
#pragma unroll
  for (int o = 1; o < 64; o <<= 1) {
    ss1 += __shfl_xor(ss1, o, 64);
    ss2 += __shfl_xor(ss2, o, 64);
    ab += __shfl_xor(ab, o, 64);
  }
  float inv1 = 1.0f / fmaxf(sqrtf(ss1), 1e-8f);
  float inv2 = 1.0f / fmaxf(sqrtf(ss2), 1e-8f);

  uint2 q;
  int lo = __builtin_amdgcn_cvt_pk_fp8_f32(a0.x * inv1, a0.y * inv1, 0, false);
  lo = __builtin_amdgcn_cvt_pk_fp8_f32(a0.z * inv1, a0.w * inv1, lo, true);
  q.x = (unsigned int)lo;
  lo = __builtin_amdgcn_cvt_pk_fp8_f32(a1.x * inv1, a1.y * inv1, 0, false);
  lo = __builtin_amdgcn_cvt_pk_fp8_f32(a1.z * inv1, a1.w * inv1, lo, true);
  q.y = (unsigned int)lo;
  ((uint2*)(zn8 + (size_t)j * DD))[lane] = q;

  lo = __builtin_amdgcn_cvt_pk_fp8_f32(b0.x * inv2, b0.y * inv2, 0, false);
  lo = __builtin_amdgcn_cvt_pk_fp8_f32(b0.z * inv2, b0.w * inv2, lo, true);
  q.x = (unsigned int)lo;
  lo = __builtin_amdgcn_cvt_pk_fp8_f32(b1.x * inv2, b1.y * inv2, 0, false);
  lo = __builtin_amdgcn_cvt_pk_fp8_f32(b1.z * inv2, b1.w * inv2, lo, true);
  q.y = (unsigned int)lo;
  ((uint2*)(zn8 + (size_t)(B_ROWS + j) * DD))[lane] = q;

  if (lane == 0) tpart[j] = 2.0f + 2.0f * ab * inv1 * inv2;  // fp32-exact target terms
  if (threadIdx.x < 8) rowsum[blockIdx.x * 8 + threadIdx.x] = 0.f;  // 1024*8 = 8192
}

// ---------- main: persistent-A fp8 GEMM + exp-rowsum ----------
// Block = 4 waves, 128 A-rows in registers (full K); 4 B-panels of
// 64 cols x 512 K staged in ONE 32KB LDS buffer (stage->sync->compute->sync).
// 1056 blocks (~4.1/CU of work) x 4 blocks/CU capacity: cross-block TLP
// hides the stage latency that the single-buffer structure serializes.
// Tiles (P, j) for j in [2P, 128), chunks of 4; mirror col-sums for j >= 2P+2.
__global__ __launch_bounds__(256, 4) void k_gemm_expsum(const unsigned char* __restrict__ zn8,
                                                        float* __restrict__ rowsum) {
  __shared__ __align__(16) char bbuf[32768];
  __shared__ float colaccum[256];

  int g = blockIdx.x;  // natural order: round-robin dispatch balances XCDs; big-P-first

  // decode (P, c): band P has ceil((128-2P)/4) chunks of 4 col-tiles
  int P = 0, off = 0;
  for (;;) {
    int nb = (131 - 2 * P) >> 2;
    if (g < off + nb) break;
    off += nb;
    ++P;
  }
  int c = g - off;
  const int j0 = 2 * P + 4 * c;
  int nt = 128 - j0; if (nt > 4) nt = 4;

  const int tid = threadIdx.x;
  const int lane = tid & 63, w = tid >> 6;
  const int lr = lane & 15, hi2 = lane >> 4;
  const char* zb = (const char*)zn8;
  const int arow0 = P * 128;

  if (tid < 256) colaccum[tid] = 0.f;

  // stage geometry: 64-row x 512B panel -> 32KB; 8 x 16B per thread;
  // linear LDS dest, inverse-swizzled global source (XOR cancels on read)
  int srow[8], scol[8];
#pragma unroll
  for (int cc = 0; cc < 8; ++cc) {
    int lo2 = cc * 4096 + tid * 16;
    srow[cc] = lo2 >> 9;
    scol[cc] = (lo2 & 511) ^ ((srow[cc] & 7) << 4);
  }

#define STAGE(rowbase) do {                                                              \
    _Pragma("unroll")                                                                    \
    for (int cc = 0; cc < 8; ++cc) {                                                     \
      const char* _s = zb + (size_t)((rowbase) + srow[cc]) * DD + scol[cc];              \
      __builtin_amdgcn_global_load_lds((__attribute__((address_space(1))) void*)_s,      \
          (__attribute__((address_space(3))) void*)(bbuf + cc * 4096 + (w << 10)),       \
          16, 0, 0);                                                                     \
    }                                                                                    \
  } while (0)

  // ---- load A panel (128 rows x 512 K fp8) into registers, two phases ----
  long2v aR[2][8];  // 64 regs: global rows 32w+16m+lr, 16B k-windows
  STAGE(arow0);            // rows 0-63
  __syncthreads();
  if (w < 2) {
#pragma unroll
    for (int m = 0; m < 2; ++m) {
      int rr = (w << 5) + (m << 4) + lr;
      const char* rowp = bbuf + rr * DD;
      int sz = (rr & 7) << 4;
#pragma unroll
      for (int p = 0; p < 8; ++p)
        aR[m][p] = *(const long2v*)(rowp + ((p * 64 + hi2 * 16) ^ sz));
    }
  }
  __syncthreads();         // reads drained before restage
  STAGE(arow0 + 64);       // rows 64-127
  __syncthreads();
  if (w >= 2) {
#pragma unroll
    for (int m = 0; m < 2; ++m) {
      int rr = ((w - 2) << 5) + (m << 4) + lr;
      const char* rowp = bbuf + rr * DD;
      int sz = (rr & 7) << 4;
#pragma unroll
      for (int p = 0; p < 8; ++p)
        aR[m][p] = *(const long2v*)(rowp + ((p * 64 + hi2 * 16) ^ sz));
    }
  }
  __syncthreads();         // A reads done; buffer free for B

  float rowacc[2][4];
#pragma unroll
  for (int m = 0; m < 2; ++m)
#pragma unroll
    for (int r = 0; r < 4; ++r) rowacc[m][r] = 0.f;

  const float Cc = 2.88539008177792681f;
  for (int t = 0; t < nt; ++t) {
    STAGE((j0 + t) * 64);
    __syncthreads();  // panel staged (stage latency hidden by other resident blocks)

    float4v acc[2][4];
#pragma unroll
    for (int m = 0; m < 2; ++m)
#pragma unroll
      for (int n = 0; n < 4; ++n) acc[m][n] = {0.f, 0.f, 0.f, 0.f};

#pragma unroll
    for (int n = 0; n < 4; ++n) {
      long2v bR[8];
      int col = (n << 4) + lr;
      const char* colp = bbuf + col * DD;
      int sz = (col & 7) << 4;
#pragma unroll
      for (int p = 0; p < 8; ++p)
        bR[p] = *(const long2v*)(colp + ((p * 64 + hi2 * 16) ^ sz));
#pragma unroll
      for (int p = 0; p < 8; ++p)
#pragma unroll
        for (int m = 0; m < 2; ++m) {
          acc[m][n] = __builtin_amdgcn_mfma_f32_16x16x32_fp8_fp8(aR[m][p][0], bR[p][0], acc[m][n], 0, 0, 0);
          acc[m][n] = __builtin_amdgcn_mfma_f32_16x16x32_fp8_fp8(aR[m][p][1], bR[p][1], acc[m][n], 0, 0, 0);
        }
    }

    // epilogue tile t: e = exp(2*dot - 2) = exp2(C*dot - C)
    // D layout: row = w*32 + m*16 + hi2*4 + r, col = (j0+t)*64 + n*16 + lr
    float colp4[4] = {0.f, 0.f, 0.f, 0.f};
#pragma unroll
    for (int m = 0; m < 2; ++m)
#pragma unroll
      for (int n = 0; n < 4; ++n)
#pragma unroll
        for (int r = 0; r < 4; ++r) {
          float e = exp2f(fmaf(acc[m][n][r], Cc, -Cc));
          rowacc[m][r] += e;
          colp4[n] += e;
        }
    if ((j0 + t) >= 2 * P + 2) {  // mirror col-sums (strictly above the diagonal block)
#pragma unroll
      for (int n = 0; n < 4; ++n) {
        float v = colp4[n];
        v += __shfl_xor(v, 16);
        v += __shfl_xor(v, 32);
        if (hi2 == 0) atomicAdd(&colaccum[(t << 6) + (n << 4) + lr], v);  // ds_add
      }
    }
    __syncthreads();  // B reads + colaccum adds done before next stage / flush
  }
#undef STAGE

  // row atomics: one per row per block (128 rows)
#pragma unroll
  for (int m = 0; m < 2; ++m)
#pragma unroll
    for (int r = 0; r < 4; ++r) {
      float v = rowacc[m][r];
      v += __shfl_xor(v, 1);
      v += __shfl_xor(v, 2);
      v += __shfl_xor(v, 4);
      v += __shfl_xor(v, 8);
      if (lr == 0)
        atomicAdd(&rowsum[arow0 + (w << 5) + (m << 4) + (hi2 << 2) + r], v);
    }
  // col mirror flush: once per block (skip the two diagonal tiles when c == 0)
  for (int idx = tid + (c == 0 ? 128 : 0); idx < nt * 64; idx += 256)
    atomicAdd(&rowsum[(j0 + (idx >> 6)) * 64 + (idx & 63)], colaccum[idx]);
}

// ---------- finalize: loss = (sum(2 + log rowsum) - sum tpart) / 8192 ----------
__global__ __launch_bounds__(1024) void k_finalize(const float* __restrict__ rowsum,
                                                   const float* __restrict__ tpart,
                                                   float* __restrict__ out) {
  int t = threadIdx.x;
  float acc = 0.f;
  for (int i = t; i < N2; i += 1024) acc += 2.0f + logf(rowsum[i]);
  for (int i = t; i < B_ROWS; i += 1024) acc -= tpart[i];
#pragma unroll
  for (int o = 32; o; o >>= 1) acc += __shfl_down(acc, o, 64);
  __shared__ float wsum[16];
  if ((t & 63) == 0) wsum[t >> 6] = acc;
  __syncthreads();
  if (t == 0) {
    float s = 0.f;
#pragma unroll
    for (int k = 0; k < 16; ++k) s += wsum[k];
    out[0] = s * (1.0f / (float)N2);
  }
}

extern "C" void kernel_launch(void* const* d_in, const int* in_sizes, int n_in,
                              void* d_out, int out_size, void* d_ws, size_t ws_size,
                              hipStream_t stream) {
  const float* f1 = (const float*)d_in[0];
  const float* f2 = (const float*)d_in[1];
  float* out = (float*)d_out;
  char* ws = (char*)d_ws;

  unsigned char* zn8 = (unsigned char*)ws;               // 8192*512 = 4 MB fp8
  float* rowsum = (float*)(ws + (size_t)N2 * DD);        // 32 KB
  float* tpart = rowsum + N2;                            // 16 KB

  k_norm_tgt<<<B_ROWS / 4, 256, 0, stream>>>(f1, f2, zn8, tpart, rowsum);
  k_gemm_expsum<<<NBLK, 256, 0, stream>>>(zn8, rowsum);
  k_finalize<<<1, 1024, 0, stream>>>(rowsum, tpart, out);
}

// Round 17
// 64.227 us; speedup vs baseline: 1.7736x; 1.1025x over previous
//
#include <hip/hip_runtime.h>
#include <hip/hip_bf16.h>

#define B_ROWS 4096
#define N2 8192
#define DD 512
#define NBLK 1056  // sum over P=0..63 of ceil((128-2P)/4)

typedef __attribute__((ext_vector_type(4))) float float4v;
typedef __attribute__((ext_vector_type(2))) long long2v;

// ---------- normalize + targets + rowsum-zero, one wave per row-pair ----------
// Outputs zn as fp8 e4m3 (OCP), 512 B per row.
__global__ __launch_bounds__(256) void k_norm_tgt(const float* __restrict__ f1,
                                                  const float* __restrict__ f2,
                                                  unsigned char* __restrict__ zn8,
                                                  float* __restrict__ tpart,
                                                  float* __restrict__ rowsum) {
  int w = threadIdx.x >> 6, lane = threadIdx.x & 63;
  int j = blockIdx.x * 4 + w;  // pair index 0..4095
  const float4* s1 = (const float4*)(f1 + (size_t)j * DD);
  const float4* s2 = (const float4*)(f2 + (size_t)j * DD);
  float4 a0 = s1[lane * 2], a1 = s1[lane * 2 + 1];
  float4 b0 = s2[lane * 2], b1 = s2[lane * 2 + 1];
  float ss1 = a0.x * a0.x + a0.y * a0.y + a0.z * a0.z + a0.w * a0.w +
              a1.x * a1.x + a1.y * a1.y + a1.z * a1.z + a1.w * a1.w;
  float ss2 = b0.x * b0.x + b0.y * b0.y + b0.z * b0.z + b0.w * b0.w +
              b1.x * b1.x + b1.y * b1.y + b1.z * b1.z + b1.w * b1.w;
  float ab = a0.x * b0.x + a0.y * b0.y + a0.z * b0.z + a0.w * b0.w +
             a1.x * b1.x + a1.y * b1.y + a1.z * b1.z + a1.w * b1.w;
#pragma unroll
  for (int o = 1; o < 64; o <<= 1) {
    ss1 += __shfl_xor(ss1, o, 64);
    ss2 += __shfl_xor(ss2, o, 64);
    ab += __shfl_xor(ab, o, 64);
  }
  float inv1 = 1.0f / fmaxf(sqrtf(ss1), 1e-8f);
  float inv2 = 1.0f / fmaxf(sqrtf(ss2), 1e-8f);

  uint2 q;
  int lo = __builtin_amdgcn_cvt_pk_fp8_f32(a0.x * inv1, a0.y * inv1, 0, false);
  lo = __builtin_amdgcn_cvt_pk_fp8_f32(a0.z * inv1, a0.w * inv1, lo, true);
  q.x = (unsigned int)lo;
  lo = __builtin_amdgcn_cvt_pk_fp8_f32(a1.x * inv1, a1.y * inv1, 0, false);
  lo = __builtin_amdgcn_cvt_pk_fp8_f32(a1.z * inv1, a1.w * inv1, lo, true);
  q.y = (unsigned int)lo;
  ((uint2*)(zn8 + (size_t)j * DD))[lane] = q;

  lo = __builtin_amdgcn_cvt_pk_fp8_f32(b0.x * inv2, b0.y * inv2, 0, false);
  lo = __builtin_amdgcn_cvt_pk_fp8_f32(b0.z * inv2, b0.w * inv2, lo, true);
  q.x = (unsigned int)lo;
  lo = __builtin_amdgcn_cvt_pk_fp8_f32(b1.x * inv2, b1.y * inv2, 0, false);
  lo = __builtin_amdgcn_cvt_pk_fp8_f32(b1.z * inv2, b1.w * inv2, lo, true);
  q.y = (unsigned int)lo;
  ((uint2*)(zn8 + (size_t)(B_ROWS + j) * DD))[lane] = q;

  if (lane == 0) tpart[j] = 2.0f + 2.0f * ab * inv1 * inv2;  // fp32-exact target terms
  if (threadIdx.x < 8) rowsum[blockIdx.x * 8 + threadIdx.x] = 0.f;  // 1024*8 = 8192
}

// ---------- main: persistent-A fp8 GEMM + exp-rowsum ----------
// Block = 4 waves, 128 A-rows loaded DIRECTLY global->regs (one-time, vmcnt(0)
// drained). 4 B-panels (64 cols x 512 K) in a 2x32KB LDS double buffer:
// STAGE(t+1) at loop top, counted vmcnt(8) (never 0 mid-loop), raw barriers.
// 4-bit XOR swizzle ((row&15)<<4) -> conflict-free ds_read_b128.
// Tiles (P, j) for j in [2P, 128); mirror col-sums for j >= 2P+2.
__global__ __launch_bounds__(256, 2) void k_gemm_expsum(const unsigned char* __restrict__ zn8,
                                                        float* __restrict__ rowsum) {
  __shared__ __align__(16) char bbuf[2][32768];
  __shared__ float colaccum[256];

  int g = blockIdx.x;  // natural order: round-robin dispatch balances XCDs

  // decode (P, c): band P has ceil((128-2P)/4) chunks of 4 col-tiles
  int P = 0, off = 0;
  for (;;) {
    int nb = (131 - 2 * P) >> 2;
    if (g < off + nb) break;
    off += nb;
    ++P;
  }
  int c = g - off;
  const int j0 = 2 * P + 4 * c;
  int nt = 128 - j0; if (nt > 4) nt = 4;

  const int tid = threadIdx.x;
  const int lane = tid & 63, w = tid >> 6;
  const int lr = lane & 15, hi2 = lane >> 4;
  const char* zb = (const char*)zn8;
  const int arow0 = P * 128;

  if (tid < 256) colaccum[tid] = 0.f;

  // ---- A panel: 32 rows/wave, full K, direct global->regs (one time) ----
  long2v aR[2][8];  // 64 VGPR: row = arow0 + w*32 + m*16 + lr, k-window hi2*16 + p*64
#pragma unroll
  for (int m = 0; m < 2; ++m) {
    const char* rowp = zb + (size_t)(arow0 + (w << 5) + (m << 4) + lr) * DD + hi2 * 16;
#pragma unroll
    for (int p = 0; p < 8; ++p)
      aR[m][p] = *(const long2v*)(rowp + p * 64);
  }
  asm volatile("s_waitcnt vmcnt(0)" ::: "memory");  // A in regs; vm queue empty
  __builtin_amdgcn_sched_barrier(0);

  // stage geometry: 64-row x 512B panel -> 32KB; 8 x 16B per thread;
  // linear LDS dest, inverse-swizzled global source (4-bit XOR cancels on read)
  int srow[8], scol[8];
#pragma unroll
  for (int cc = 0; cc < 8; ++cc) {
    int lo2 = cc * 4096 + tid * 16;
    srow[cc] = lo2 >> 9;
    scol[cc] = (lo2 & 511) ^ ((srow[cc] & 15) << 4);
  }

#define STAGE(bufp, rowbase) do {                                                        \
    _Pragma("unroll")                                                                    \
    for (int cc = 0; cc < 8; ++cc) {                                                     \
      const char* _s = zb + (size_t)((rowbase) + srow[cc]) * DD + scol[cc];              \
      __builtin_amdgcn_global_load_lds((__attribute__((address_space(1))) void*)_s,      \
          (__attribute__((address_space(3))) void*)((bufp) + cc * 4096 + (w << 10)),     \
          16, 0, 0);                                                                     \
    }                                                                                    \
  } while (0)

  float rowacc[2][4];
#pragma unroll
  for (int m = 0; m < 2; ++m)
#pragma unroll
    for (int r = 0; r < 4; ++r) rowacc[m][r] = 0.f;

  const float Cc = 2.88539008177792681f;

  STAGE((char*)bbuf[0], j0 * 64);  // prologue: tile 0 in flight

  for (int t = 0; t < nt; ++t) {
    if (t + 1 < nt) {
      STAGE((char*)bbuf[(t + 1) & 1], (j0 + t + 1) * 64);   // next tile in flight
      asm volatile("s_waitcnt vmcnt(8)" ::: "memory");       // tile t landed (8 newest pending)
    } else {
      asm volatile("s_waitcnt vmcnt(0)" ::: "memory");
    }
    __builtin_amdgcn_sched_barrier(0);
    __builtin_amdgcn_s_barrier();  // b1: tile t visible to all waves

    const char* bb = (const char*)bbuf[t & 1];
    float4v acc[2][4];
#pragma unroll
    for (int m = 0; m < 2; ++m)
#pragma unroll
      for (int n = 0; n < 4; ++n) acc[m][n] = {0.f, 0.f, 0.f, 0.f};

#pragma unroll
    for (int n = 0; n < 4; ++n) {
      long2v bR[8];
      int col = (n << 4) + lr;
      const char* colp = bb + col * DD;
      int sz = (col & 15) << 4;
#pragma unroll
      for (int p = 0; p < 8; ++p)
        bR[p] = *(const long2v*)(colp + ((p * 64 + hi2 * 16) ^ sz));
#pragma unroll
      for (int p = 0; p < 8; ++p)
#pragma unroll
        for (int m = 0; m < 2; ++m) {
          acc[m][n] = __builtin_amdgcn_mfma_f32_16x16x32_fp8_fp8(aR[m][p][0], bR[p][0], acc[m][n], 0, 0, 0);
          acc[m][n] = __builtin_amdgcn_mfma_f32_16x16x32_fp8_fp8(aR[m][p][1], bR[p][1], acc[m][n], 0, 0, 0);
        }
    }

    // epilogue tile t: e = exp(2*dot - 2) = exp2(C*dot - C)
    // D layout: row = w*32 + m*16 + hi2*4 + r, col = (j0+t)*64 + n*16 + lr
    float colp4[4] = {0.f, 0.f, 0.f, 0.f};
#pragma unroll
    for (int m = 0; m < 2; ++m)
#pragma unroll
      for (int n = 0; n < 4; ++n)
#pragma unroll
        for (int r = 0; r < 4; ++r) {
          float e = exp2f(fmaf(acc[m][n][r], Cc, -Cc));
          rowacc[m][r] += e;
          colp4[n] += e;
        }
    if ((j0 + t) >= 2 * P + 2) {  // mirror col-sums (strictly above the diagonal block)
#pragma unroll
      for (int n = 0; n < 4; ++n) {
        float v = colp4[n];
        v += __shfl_xor(v, 16);
        v += __shfl_xor(v, 32);
        if (hi2 == 0) atomicAdd(&colaccum[(t << 6) + (n << 4) + lr], v);  // ds_add
      }
    }
    __builtin_amdgcn_s_barrier();  // b2: all waves' reads of buf[t&1] consumed
  }
#undef STAGE

  // row atomics: one per row per block (128 rows)
#pragma unroll
  for (int m = 0; m < 2; ++m)
#pragma unroll
    for (int r = 0; r < 4; ++r) {
      float v = rowacc[m][r];
      v += __shfl_xor(v, 1);
      v += __shfl_xor(v, 2);
      v += __shfl_xor(v, 4);
      v += __shfl_xor(v, 8);
      if (lr == 0)
        atomicAdd(&rowsum[arow0 + (w << 5) + (m << 4) + (hi2 << 2) + r], v);
    }

  // col mirror flush: once per block (skip the two diagonal tiles when c == 0)
  __syncthreads();  // lgkmcnt(0) drain: all ds_adds visible
  for (int idx = tid + (c == 0 ? 128 : 0); idx < nt * 64; idx += 256)
    atomicAdd(&rowsum[(j0 + (idx >> 6)) * 64 + (idx & 63)], colaccum[idx]);
}

// ---------- finalize: loss = (sum(2 + log rowsum) - sum tpart) / 8192 ----------
__global__ __launch_bounds__(1024) void k_finalize(const float* __restrict__ rowsum,
                                                   const float* __restrict__ tpart,
                                                   float* __restrict__ out) {
  int t = threadIdx.x;
  float acc = 0.f;
  for (int i = t; i < N2; i += 1024) acc += 2.0f + logf(rowsum[i]);
  for (int i = t; i < B_ROWS; i += 1024) acc -= tpart[i];
#pragma unroll
  for (int o = 32; o; o >>= 1) acc += __shfl_down(acc, o, 64);
  __shared__ float wsum[16];
  if ((t & 63) == 0) wsum[t >> 6] = acc;
  __syncthreads();
  if (t == 0) {
    float s = 0.f;
#pragma unroll
    for (int k = 0; k < 16; ++k) s += wsum[k];
    out[0] = s * (1.0f / (float)N2);
  }
}

extern "C" void kernel_launch(void* const* d_in, const int* in_sizes, int n_in,
                              void* d_out, int out_size, void* d_ws, size_t ws_size,
                              hipStream_t stream) {
  const float* f1 = (const float*)d_in[0];
  const float* f2 = (const float*)d_in[1];
  float* out = (float*)d_out;
  char* ws = (char*)d_ws;

  unsigned char* zn8 = (unsigned char*)ws;               // 8192*512 = 4 MB fp8
  float* rowsum = (float*)(ws + (size_t)N2 * DD);        // 32 KB
  float* tpart = rowsum + N2;                            // 16 KB

  k_norm_tgt<<<B_ROWS / 4, 256, 0, stream>>>(f1, f2, zn8, tpart, rowsum);
  k_gemm_expsum<<<NBLK, 256, 0, stream>>>(zn8, rowsum);
  k_finalize<<<1, 1024, 0, stream>>>(rowsum, tpart, out);
}